// Round 3
// baseline (357.469 us; speedup 1.0000x reference)
//
#include <hip/hip_runtime.h>

#define NN 100000
#define NE 1600000
#define DF 128
#define DOUT 64
#define NG 128
#define NB 391      // ceil(NN/256) buckets of 256 nodes
#define EPB 8192    // edges per block in binning passes
#define NBLKA ((NE + EPB - 1) / EPB)  // 196
#define NBLKX 6250  // prepx blocks: NN*DF/8/256
#define PCH 8       // pool chunks per graph
#define NAGB (NN / 16)  // agg blocks: 16 nodes per block (4 waves x 4 nodes)
#define NBF ((NN + 63) / 64)  // fused blocks: 64 nodes per block (16 per wave)

typedef short short8 __attribute__((ext_vector_type(8)));
typedef float floatx4 __attribute__((ext_vector_type(4)));
typedef float floatx2 __attribute__((ext_vector_type(2)));

__device__ __forceinline__ unsigned short f2bf(float f) {
    unsigned int b = __float_as_uint(f);
    unsigned int r = (b + 0x7fffu + ((b >> 16) & 1u)) >> 16;
    return (unsigned short)r;
}
__device__ __forceinline__ float bf2f_lo(unsigned int v) { return __uint_as_float(v << 16); }
__device__ __forceinline__ float bf2f_hi(unsigned int v) { return __uint_as_float(v & 0xffff0000u); }

// physical feature index p -> logical feature c.
// p = g*64 + lm*4 + u  (g:0..1, lm:0..15, u:0..3), c = (g*4+u)*16 + lm
__device__ __forceinline__ int phi(int p) {
    return (((p >> 6) << 2) + (p & 3)) * 16 + ((p >> 2) & 15);
}

// ---------------- fused init: graph bounds + prepw (bf16 frags) ----------------

__global__ __launch_bounds__(256) void k_init(const int* __restrict__ batch,
                                              int* __restrict__ gstart,
                                              const float* __restrict__ W1,
                                              const float* __restrict__ W2,
                                              const float* __restrict__ W3,
                                              unsigned short* __restrict__ O1,
                                              unsigned short* __restrict__ O2,
                                              unsigned short* __restrict__ O3) {
    int blk = blockIdx.x;
    if (blk == 0) {
        int g = threadIdx.x;
        if (g > NG) return;
        int lo = 0, hi = NN;
        while (lo < hi) {
            int mid = (lo + hi) >> 1;
            if (batch[mid] < g) lo = mid + 1; else hi = mid;
        }
        gstart[g] = lo;
    } else {
        int bb = blk - 1;
        const float* W = (bb >= 16) ? W3 : (bb >= 8) ? W2 : W1;
        unsigned short* O = (bb >= 16) ? O3 : (bb >= 8) ? O2 : O1;
        int idx = (bb & 7) * 256 + threadIdx.x;
        int l = idx & 63;
        int s = (idx >> 6) & 3;
        int tt = idx >> 8;
        int k0 = s * 32 + (l >> 4) * 8;
        int c = tt * 16 + (l & 15);
        unsigned short o[8];
#pragma unroll
        for (int j = 0; j < 8; j++) o[j] = f2bf(W[phi(k0 + j) * DF + c]);
        *(short8*)&O[idx * 8] = *(short8*)o;
    }
}

// ---------------- fused: per-block dst histogram (plain stores) + prepx ----------------

__global__ __launch_bounds__(256) void k_pre(const int* __restrict__ dst,
                                             int* __restrict__ hist,
                                             const float* __restrict__ x,
                                             unsigned short* __restrict__ xb) {
    __shared__ int lh[NB];
    int t = threadIdx.x;
    if (blockIdx.x < NBLKA) {
        for (int i = t; i < NB; i += 256) lh[i] = 0;
        __syncthreads();
        int e0 = blockIdx.x * EPB;
        int e1 = min(e0 + EPB, NE);
        for (int e = e0 + t; e < e1; e += 256) atomicAdd(&lh[dst[e] >> 8], 1);
        __syncthreads();
        for (int i = t; i < NB; i += 256) hist[blockIdx.x * NB + i] = lh[i];
    } else {
        size_t i = ((size_t)(blockIdx.x - NBLKA) * 256 + t) * 8;
        size_t rb = i & ~(size_t)127;
        int p0 = (int)(i & 127);
        unsigned short o[8];
#pragma unroll
        for (int j = 0; j < 8; j++) o[j] = f2bf(x[rb + phi(p0 + j)]);
        *(short8*)&xb[i] = *(short8*)o;
    }
}

// one block per bucket: exclusive-scan hist[*][b] over blocks (in place),
// bucket total -> bhist[b]. Deterministic replacement for the global atomics.
__global__ __launch_bounds__(256) void k_hscan(int* __restrict__ hist,
                                               int* __restrict__ bhist) {
    __shared__ int sh[256];
    int b = blockIdx.x, t = threadIdx.x;
    int v = (t < NBLKA) ? hist[t * NB + b] : 0;
    sh[t] = v;
    __syncthreads();
    for (int off = 1; off < 256; off <<= 1) {
        int a = (t >= off) ? sh[t - off] : 0;
        __syncthreads();
        sh[t] += a;
        __syncthreads();
    }
    if (t < NBLKA) hist[t * NB + b] = sh[t] - v;
    if (t == 255) bhist[b] = sh[255];
}

__global__ __launch_bounds__(512) void k_bscan(const int* __restrict__ bhist,
                                               int* __restrict__ bbase) {
    __shared__ int sh[512];
    int t = threadIdx.x;
    int v = (t < NB) ? bhist[t] : 0;
    sh[t] = v;
    __syncthreads();
    for (int off = 1; off < 512; off <<= 1) {
        int a = (t >= off) ? sh[t - off] : 0;
        __syncthreads();
        sh[t] += a;
        __syncthreads();
    }
    if (t < NB) bbase[t] = sh[t] - v;
    if (t == NB - 1) bbase[NB] = sh[t];
}

// scatter only: bases are precomputed (bbase + per-block prefix), LDS atomics
// give within-chunk offsets. No global atomics at all.
__global__ __launch_bounds__(256) void k_pairs(const int* __restrict__ src,
                                               const int* __restrict__ dst,
                                               const int* __restrict__ hist,
                                               const int* __restrict__ bbase,
                                               int2* __restrict__ ebuf) {
    __shared__ int lh[NB];
    __shared__ int lbase[NB];
    int t = threadIdx.x;
    for (int i = t; i < NB; i += 256) {
        lh[i] = 0;
        lbase[i] = bbase[i] + hist[blockIdx.x * NB + i];
    }
    __syncthreads();
    int e0 = blockIdx.x * EPB;
    int e1 = min(e0 + EPB, NE);
    for (int e = e0 + t; e < e1; e += 256) {
        int s = src[e], d = dst[e];
        int bk = d >> 8;
        int off = atomicAdd(&lh[bk], 1);
        ebuf[lbase[bk] + off] = make_int2(s, d);
    }
}

// col stores BYTE offsets (src*DF) for gather fp8 table (128 B rows)
__global__ __launch_bounds__(256) void k_build(const int2* __restrict__ ebuf,
                                               const int* __restrict__ bbase,
                                               int* __restrict__ rowptr,
                                               float* __restrict__ dinv,
                                               int* __restrict__ col) {
    __shared__ int deg[256];
    __shared__ int lst[256];
    int b = blockIdx.x, t = threadIdx.x;
    int n0 = b << 8;
    int node = n0 + t;
    deg[t] = 0;
    __syncthreads();
    int e0 = bbase[b], e1 = bbase[b + 1];
    for (int e = e0 + t; e < e1; e += 256) atomicAdd(&deg[ebuf[e].y - n0], 1);
    __syncthreads();
    int v = deg[t];
    lst[t] = v;
    __syncthreads();
    for (int off = 1; off < 256; off <<= 1) {
        int a = (t >= off) ? lst[t - off] : 0;
        __syncthreads();
        lst[t] += a;
        __syncthreads();
    }
    int mystart = e0 + lst[t] - v;
    if (node < NN) {
        rowptr[node] = mystart;
        dinv[node] = rsqrtf((float)(v + 1));  // +1 self-loop
    }
    if (b == NB - 1 && t == 255) rowptr[NN] = e1;
    lst[t] = mystart;
    __syncthreads();
    for (int e = e0 + t; e < e1; e += 256) {
        int2 pr = ebuf[e];
        int p = atomicAdd(&lst[pr.y - n0], 1);
        col[p] = pr.x * DF;
    }
}

// ---------------- per-layer compute ----------------

// shared aggregation core: one 16-lane sub aggregates node n's in-edges + self
// loop, applies dinv scale + bias + relu -> o[8] (physical feature layout).
__device__ __forceinline__ void agg_node(const unsigned char* __restrict__ fs8,
                                         const int* __restrict__ colb,
                                         int n, int foff, int e0, int e1,
                                         float dvn, const float* bias,
                                         float* o) {
    floatx2 acc0 = {0.f, 0.f}, acc1 = {0.f, 0.f}, acc2 = {0.f, 0.f}, acc3 = {0.f, 0.f};
    for (int base = e0; base < e1; base += 8) {
        int cb[8];
#pragma unroll
        for (int k = 0; k < 8; k++) cb[k] = colb[min(base + k, e1 - 1)];
        uint2 vv[8];
#pragma unroll
        for (int k = 0; k < 8; k++) vv[k] = *(const uint2*)&fs8[(size_t)cb[k] + foff];
#pragma unroll
        for (int k = 0; k < 8; k++) {
            if (base + k < e1) {
                acc0 += __builtin_amdgcn_cvt_pk_f32_fp8(vv[k].x, false);
                acc1 += __builtin_amdgcn_cvt_pk_f32_fp8(vv[k].x, true);
                acc2 += __builtin_amdgcn_cvt_pk_f32_fp8(vv[k].y, false);
                acc3 += __builtin_amdgcn_cvt_pk_f32_fp8(vv[k].y, true);
            }
        }
    }
    // self-loop row (fp8, dinv[src] already folded in)
    uint2 sv = *(const uint2*)&fs8[(size_t)n * DF + foff];
    acc0 += __builtin_amdgcn_cvt_pk_f32_fp8(sv.x, false);
    acc1 += __builtin_amdgcn_cvt_pk_f32_fp8(sv.x, true);
    acc2 += __builtin_amdgcn_cvt_pk_f32_fp8(sv.y, false);
    acc3 += __builtin_amdgcn_cvt_pk_f32_fp8(sv.y, true);

    float a[8] = {acc0.x, acc0.y, acc1.x, acc1.y, acc2.x, acc2.y, acc3.x, acc3.y};
#pragma unroll
    for (int j = 0; j < 8; j++) o[j] = fmaxf(dvn * a[j] + bias[j], 0.f);
}

// fs8[r] = fp8( dinv[r] * X[r] @ W ), bf16 MFMA (weights stay bf16 for precision)
__global__ __launch_bounds__(256) void k_gemm(const unsigned short* __restrict__ X,
                                              const unsigned short* __restrict__ Wb,
                                              const float* __restrict__ dinv,
                                              unsigned char* __restrict__ fs8) {
    int t = threadIdx.x;
    int wave = t >> 6, l = t & 63;
    int r0 = blockIdx.x * 64 + wave * 16;
    int lm = l & 15, q = l >> 4;

    int arow = r0 + lm;
    if (arow >= NN) arow = NN - 1;
    const unsigned short* xrow = X + (size_t)arow * DF + q * 8;
    short8 af0 = *(const short8*)(xrow);
    short8 af1 = *(const short8*)(xrow + 32);
    short8 af2 = *(const short8*)(xrow + 64);
    short8 af3 = *(const short8*)(xrow + 96);

    int orow = r0 + q * 4;
    float dv[4];
#pragma unroll
    for (int j = 0; j < 4; j++) dv[j] = (orow + j < NN) ? dinv[orow + j] : 0.f;

    float res[4][8];
#pragma unroll
    for (int tt = 0; tt < 8; tt++) {
        floatx4 acc = {0.f, 0.f, 0.f, 0.f};
        const unsigned short* wp = Wb + ((size_t)(tt * 4) * 64 + l) * 8;
        acc = __builtin_amdgcn_mfma_f32_16x16x32_bf16(af0, *(const short8*)(wp), acc, 0, 0, 0);
        acc = __builtin_amdgcn_mfma_f32_16x16x32_bf16(af1, *(const short8*)(wp + 512), acc, 0, 0, 0);
        acc = __builtin_amdgcn_mfma_f32_16x16x32_bf16(af2, *(const short8*)(wp + 1024), acc, 0, 0, 0);
        acc = __builtin_amdgcn_mfma_f32_16x16x32_bf16(af3, *(const short8*)(wp + 1536), acc, 0, 0, 0);
#pragma unroll
        for (int j = 0; j < 4; j++) res[j][tt] = acc[j] * dv[j];
    }

#pragma unroll
    for (int g = 0; g < 2; g++) {
#pragma unroll
        for (int j = 0; j < 4; j++) {
            int r = orow + j;
            if (r >= NN) continue;
            unsigned int w8 = __builtin_amdgcn_cvt_pk_fp8_f32(res[j][g * 4 + 0], res[j][g * 4 + 1], 0, false);
            w8 = __builtin_amdgcn_cvt_pk_fp8_f32(res[j][g * 4 + 2], res[j][g * 4 + 3], w8, true);
            *(unsigned int*)&fs8[(size_t)r * DF + g * 64 + lm * 4] = w8;
        }
    }
}

// fused agg(layer i) -> gemm(layer i+1): 64 nodes/block, 16/wave.
// Phase 1: wave aggregates its 16 nodes (4 passes of 4), bf16 rows into a
// wave-private LDS tile, XOR-swizzled (slot ^= row) so phase-2 ds_read_b128
// at 256 B row stride is conflict-free.
// Phase 2: identical to k_gemm but A-frags come from LDS; writes fp8 out.
// Removes the 51.2 MB/boundary ob round-trip through HBM.
__global__ __launch_bounds__(256, 6) void k_fused(const unsigned char* __restrict__ fs8_in,
                                                  const int* __restrict__ colb,
                                                  const int* __restrict__ rowptr,
                                                  const float* __restrict__ dinv,
                                                  const float* __restrict__ b,
                                                  const unsigned short* __restrict__ Wb,
                                                  unsigned char* __restrict__ fs8_out) {
    __shared__ unsigned short tile[4][16 * DF];  // 4 KB per wave
    int t = threadIdx.x;
    int w = t >> 6, lane = t & 63;
    int sub = lane >> 4, fo = lane & 15;
    int foff = fo * 8;
    int r0 = blockIdx.x * 64 + w * 16;

    float bias[8];
#pragma unroll
    for (int j = 0; j < 8; j++) bias[j] = b[phi(foff + j)];

    unsigned short* mytile = &tile[w][0];

#pragma unroll 1
    for (int pass = 0; pass < 4; ++pass) {
        int row = pass * 4 + sub;
        int n = r0 + row;
        int nc = (n < NN) ? n : (NN - 1);  // clamp: OOB rows compute garbage, never stored
        float dvn = dinv[nc];
        int e0 = rowptr[nc], e1 = rowptr[nc + 1];
        float o[8];
        agg_node(fs8_in, colb, nc, foff, e0, e1, dvn, bias, o);
        uint4 pk;
        pk.x = (unsigned int)f2bf(o[0]) | ((unsigned int)f2bf(o[1]) << 16);
        pk.y = (unsigned int)f2bf(o[2]) | ((unsigned int)f2bf(o[3]) << 16);
        pk.z = (unsigned int)f2bf(o[4]) | ((unsigned int)f2bf(o[5]) << 16);
        pk.w = (unsigned int)f2bf(o[6]) | ((unsigned int)f2bf(o[7]) << 16);
        *(uint4*)&mytile[row * DF + ((fo ^ row) * 8)] = pk;  // swizzled slot
    }
    __syncthreads();

    // ---- phase 2: MFMA on this wave's 16-row tile ----
    int lm = lane & 15, q = lane >> 4;
    short8 af[4];
#pragma unroll
    for (int k = 0; k < 4; k++)
        af[k] = *(const short8*)&mytile[lm * DF + (((q + 4 * k) ^ lm) * 8)];

    int orow = r0 + q * 4;
    float dv[4];
#pragma unroll
    for (int j = 0; j < 4; j++) dv[j] = (orow + j < NN) ? dinv[orow + j] : 0.f;

#pragma unroll
    for (int g = 0; g < 2; g++) {
        float res[4][4];
#pragma unroll
        for (int u = 0; u < 4; u++) {
            int tt = g * 4 + u;
            floatx4 acc = {0.f, 0.f, 0.f, 0.f};
            const unsigned short* wp = Wb + ((size_t)(tt * 4) * 64 + lane) * 8;
            acc = __builtin_amdgcn_mfma_f32_16x16x32_bf16(af[0], *(const short8*)(wp), acc, 0, 0, 0);
            acc = __builtin_amdgcn_mfma_f32_16x16x32_bf16(af[1], *(const short8*)(wp + 512), acc, 0, 0, 0);
            acc = __builtin_amdgcn_mfma_f32_16x16x32_bf16(af[2], *(const short8*)(wp + 1024), acc, 0, 0, 0);
            acc = __builtin_amdgcn_mfma_f32_16x16x32_bf16(af[3], *(const short8*)(wp + 1536), acc, 0, 0, 0);
#pragma unroll
            for (int j = 0; j < 4; j++) res[j][u] = acc[j] * dv[j];
        }
#pragma unroll
        for (int j = 0; j < 4; j++) {
            int r = orow + j;
            if (r >= NN) continue;
            unsigned int w8 = __builtin_amdgcn_cvt_pk_fp8_f32(res[j][0], res[j][1], 0, false);
            w8 = __builtin_amdgcn_cvt_pk_fp8_f32(res[j][2], res[j][3], w8, true);
            *(unsigned int*)&fs8_out[(size_t)r * DF + g * 64 + lm * 4] = w8;
        }
    }
}

// standalone agg for the last layer (output feeds pooling)
__global__ __launch_bounds__(256) void k_agg(const unsigned char* __restrict__ fs8,
                                             const int* __restrict__ colb,
                                             const int* __restrict__ rowptr,
                                             const float* __restrict__ dinv,
                                             const float* __restrict__ b,
                                             unsigned short* __restrict__ out) {
    int w = (int)((blockIdx.x * (size_t)blockDim.x + threadIdx.x) >> 6);
    int lane = threadIdx.x & 63;
    int sub = lane >> 4;
    int fo = lane & 15;
    int foff = fo * 8;
    int n = w * 4 + sub;

    float bias[8];
#pragma unroll
    for (int j = 0; j < 8; j++) bias[j] = b[phi(foff + j)];
    float dvn = dinv[n];
    int e0 = rowptr[n], e1 = rowptr[n + 1];

    float o[8];
    agg_node(fs8, colb, n, foff, e0, e1, dvn, bias, o);

    uint4 pk;
    pk.x = (unsigned int)f2bf(o[0]) | ((unsigned int)f2bf(o[1]) << 16);
    pk.y = (unsigned int)f2bf(o[2]) | ((unsigned int)f2bf(o[3]) << 16);
    pk.z = (unsigned int)f2bf(o[4]) | ((unsigned int)f2bf(o[5]) << 16);
    pk.w = (unsigned int)f2bf(o[6]) | ((unsigned int)f2bf(o[7]) << 16);
    *(uint4*)&out[(size_t)n * DF + foff] = pk;
}

// ---------------- pooling + FC ----------------

__global__ __launch_bounds__(256) void k_poolA(const unsigned short* __restrict__ h,
                                               const int* __restrict__ gstart,
                                               float* __restrict__ part) {
    __shared__ float2 red[256];
    int g = blockIdx.x >> 3, c = blockIdx.x & 7;
    int s = gstart[g], e = gstart[g + 1];
    int len = e - s;
    int cs = s + (int)(((long long)len * c) >> 3);
    int ce = s + (int)(((long long)len * (c + 1)) >> 3);
    int t = threadIdx.x;
    int fp = t & 63;
    int rs = t >> 6;
    float2 acc = make_float2(0.f, 0.f);
    for (int n = cs + rs; n < ce; n += 4) {
        unsigned int v = *(const unsigned int*)&h[(size_t)n * DF + fp * 2];
        acc.x += bf2f_lo(v);
        acc.y += bf2f_hi(v);
    }
    red[t] = acc;
    __syncthreads();
    if (rs == 0) {
        float2 a0 = red[fp], a1 = red[fp + 64], a2 = red[fp + 128], a3 = red[fp + 192];
        float2 o;
        o.x = (a0.x + a1.x) + (a2.x + a3.x);
        o.y = (a0.y + a1.y) + (a2.y + a3.y);
        *(float2*)&part[(size_t)blockIdx.x * DF + fp * 2] = o;
    }
}

// phase B + FC fused: reduce partials -> pooled (LDS, un-permuted) -> FC
__global__ __launch_bounds__(128) void k_poolfc(const float* __restrict__ part,
                                                const int* __restrict__ gstart,
                                                const float* __restrict__ Wfc,
                                                const float* __restrict__ bfc,
                                                float* __restrict__ out) {
    __shared__ float pl[DF];
    int g = blockIdx.x;
    int f = threadIdx.x;
    float s = 0.f;
#pragma unroll
    for (int c = 0; c < PCH; c++) s += part[(size_t)(g * PCH + c) * DF + f];
    int cnt = gstart[g + 1] - gstart[g];
    pl[phi(f)] = s / (float)max(cnt, 1);
    __syncthreads();
    if (f < DOUT) {
        float acc = bfc[f];
        for (int k = 0; k < DF; k++) acc += pl[k] * Wfc[k * DOUT + f];
        out[g * DOUT + f] = acc;
    }
}

// ---------------- launch ----------------

extern "C" void kernel_launch(void* const* d_in, const int* in_sizes, int n_in,
                              void* d_out, int out_size, void* d_ws, size_t ws_size,
                              hipStream_t stream) {
    const float* x     = (const float*)d_in[0];
    const int*   ei    = (const int*)d_in[1];
    const int*   batch = (const int*)d_in[2];
    const float* W1 = (const float*)d_in[3];
    const float* b1 = (const float*)d_in[4];
    const float* W2 = (const float*)d_in[5];
    const float* b2 = (const float*)d_in[6];
    const float* W3 = (const float*)d_in[7];
    const float* b3 = (const float*)d_in[8];
    const float* Wfc = (const float*)d_in[9];
    const float* bfc = (const float*)d_in[10];
    float* out = (float*)d_out;

    char* p = (char*)d_ws;
    unsigned short* xb = (unsigned short*)p;  p += (size_t)NN * DF * sizeof(short);
    unsigned short* ob = (unsigned short*)p;  p += (size_t)NN * DF * sizeof(short);
    unsigned char*  fs8a = (unsigned char*)p; p += (size_t)NN * DF;
    unsigned char*  fs8b = (unsigned char*)p; p += (size_t)NN * DF;
    unsigned short* Wb1 = (unsigned short*)p; p += 16384 * sizeof(short);
    unsigned short* Wb2 = (unsigned short*)p; p += 16384 * sizeof(short);
    unsigned short* Wb3 = (unsigned short*)p; p += 16384 * sizeof(short);
    float* dinv = (float*)p;           p += (size_t)NN * sizeof(float);
    int* rowptr = (int*)p;             p += (size_t)(NN + 4) * sizeof(int);
    int* col    = (int*)p;             p += (size_t)NE * sizeof(int);
    int2* ebuf  = (int2*)p;            p += (size_t)NE * sizeof(int2);
    int* bhist  = (int*)p;             p += (size_t)(NB + 4) * sizeof(int);
    int* bbase  = (int*)p;             p += (size_t)(NB + 4) * sizeof(int);
    int* hist   = (int*)p;             p += (size_t)NBLKA * NB * sizeof(int);
    int* gstart = (int*)p;             p += (size_t)(NG + 4) * sizeof(int);
    float* part = (float*)p;           p += (size_t)NG * PCH * DF * sizeof(float);

    const int* e_src = ei;
    const int* e_dst = ei + NE;

    // init (bounds + 3x bf16 prepw) ; binning (plain-store hist) + prepx fused
    k_init<<<25, 256, 0, stream>>>(batch, gstart, W1, W2, W3, Wb1, Wb2, Wb3);
    k_pre<<<NBLKA + NBLKX, 256, 0, stream>>>(e_dst, hist, x, xb);
    k_hscan<<<NB, 256, 0, stream>>>(hist, bhist);
    k_bscan<<<1, 512, 0, stream>>>(bhist, bbase);
    k_pairs<<<NBLKA, 256, 0, stream>>>(e_src, e_dst, hist, bbase, ebuf);
    k_build<<<NB, 256, 0, stream>>>(ebuf, bbase, rowptr, dinv, col);

    int ggrid = (NN + 63) / 64;

    // layer 1 gemm, then fused [agg1+gemm2], [agg2+gemm3], final agg3
    k_gemm<<<ggrid, 256, 0, stream>>>(xb, Wb1, dinv, fs8a);
    k_fused<<<NBF, 256, 0, stream>>>(fs8a, col, rowptr, dinv, b1, Wb2, fs8b);
    k_fused<<<NBF, 256, 0, stream>>>(fs8b, col, rowptr, dinv, b2, Wb3, fs8a);
    k_agg<<<NAGB, 256, 0, stream>>>(fs8a, col, rowptr, dinv, b3, ob);

    // pool + fc
    k_poolA<<<NG * PCH, 256, 0, stream>>>(ob, gstart, part);
    k_poolfc<<<NG, 128, 0, stream>>>(part, gstart, Wfc, bfc, out);
}

// Round 4
// 351.889 us; speedup vs baseline: 1.0159x; 1.0159x over previous
//
#include <hip/hip_runtime.h>

#define NN 100000
#define NE 1600000
#define DF 128
#define DOUT 64
#define NG 128
#define NB 391      // ceil(NN/256) buckets of 256 nodes
#define EPB 8192    // edges per block in binning passes
#define NBLKA ((NE + EPB - 1) / EPB)  // 196
#define PCH 8       // pool chunks per graph
#define NAGB (NN / 16)  // agg blocks: 16 nodes per block (4 waves x 4 nodes)
#define ZOFF (NN * DF)  // byte offset of the fp8 zero row

typedef short short8 __attribute__((ext_vector_type(8)));
typedef float floatx4 __attribute__((ext_vector_type(4)));
typedef float floatx2 __attribute__((ext_vector_type(2)));

__device__ __forceinline__ unsigned short f2bf(float f) {
    unsigned int b = __float_as_uint(f);
    unsigned int r = (b + 0x7fffu + ((b >> 16) & 1u)) >> 16;
    return (unsigned short)r;
}
__device__ __forceinline__ float bf2f_lo(unsigned int v) { return __uint_as_float(v << 16); }
__device__ __forceinline__ float bf2f_hi(unsigned int v) { return __uint_as_float(v & 0xffff0000u); }

// physical feature index p -> logical feature c.
// p = g*64 + lm*4 + u  (g:0..1, lm:0..15, u:0..3), c = (g*4+u)*16 + lm
__device__ __forceinline__ int phi(int p) {
    return (((p >> 6) << 2) + (p & 3)) * 16 + ((p >> 2) & 15);
}

// ---------------- fused init: dst histogram + graph bounds + zero-row + prepw ----------------
// blk < NBLKA           : per-chunk dst histogram (plain stores, no global atomics)
// blk == NBLKA          : gstart binary search
// blk == NBLKA+1        : fp8 zero row + ticket reset
// blk >= NBLKA+2 (24)   : bf16 weight fragments. Wb1 in LOGICAL k-order (layer-1
//                         gemm reads x directly); Wb2/Wb3 in physical (phi) k-order.

__global__ __launch_bounds__(256) void k_init(const int* __restrict__ dst,
                                              int* __restrict__ hist,
                                              const int* __restrict__ batch,
                                              int* __restrict__ gstart,
                                              unsigned char* __restrict__ fs8,
                                              int* __restrict__ ticket,
                                              const float* __restrict__ W1,
                                              const float* __restrict__ W2,
                                              const float* __restrict__ W3,
                                              unsigned short* __restrict__ O1,
                                              unsigned short* __restrict__ O2,
                                              unsigned short* __restrict__ O3) {
    __shared__ int lh[NB];
    int blk = blockIdx.x;
    int t = threadIdx.x;
    if (blk < NBLKA) {
        for (int i = t; i < NB; i += 256) lh[i] = 0;
        __syncthreads();
        int e0 = blk * EPB;
        int e1 = min(e0 + EPB, NE);
        for (int e = e0 + t; e < e1; e += 256) atomicAdd(&lh[dst[e] >> 8], 1);
        __syncthreads();
        for (int i = t; i < NB; i += 256) hist[blk * NB + i] = lh[i];
    } else if (blk == NBLKA) {
        int g = t;
        if (g > NG) return;
        int lo = 0, hi = NN;
        while (lo < hi) {
            int mid = (lo + hi) >> 1;
            if (batch[mid] < g) lo = mid + 1; else hi = mid;
        }
        gstart[g] = lo;
    } else if (blk == NBLKA + 1) {
        if (t < 32) *(unsigned int*)&fs8[ZOFF + t * 4] = 0u;
        if (t == 32) *ticket = 0;
    } else {
        int bb = blk - (NBLKA + 2);
        const float* W = (bb >= 16) ? W3 : (bb >= 8) ? W2 : W1;
        unsigned short* O = (bb >= 16) ? O3 : (bb >= 8) ? O2 : O1;
        bool logical = (bb < 8);
        int idx = (bb & 7) * 256 + t;
        int l = idx & 63;
        int s = (idx >> 6) & 3;
        int tt = idx >> 8;
        int k0 = s * 32 + (l >> 4) * 8;
        int c = tt * 16 + (l & 15);
        unsigned short o[8];
#pragma unroll
        for (int j = 0; j < 8; j++) {
            int kk = logical ? (k0 + j) : phi(k0 + j);
            o[j] = f2bf(W[kk * DF + c]);
        }
        *(short8*)&O[idx * 8] = *(short8*)o;
    }
}

// ---------------- merged hscan + bscan (last-block ticket) ----------------
// Per bucket b: exclusive-scan hist[*][b] over the 196 chunk blocks (in place),
// bucket total -> bhist[b] (atomicExch, device scope). Last block to finish
// scans bhist into bbase. Cross-block values only via atomics (XCD-L2 safe).

__global__ __launch_bounds__(512) void k_scan(int* __restrict__ hist,
                                              int* __restrict__ bhist,
                                              int* __restrict__ bbase,
                                              int* __restrict__ ticket) {
    __shared__ int sh[512];
    __shared__ int amLast;
    int b = blockIdx.x, t = threadIdx.x;
    int v = (t < NBLKA) ? hist[t * NB + b] : 0;
    sh[t] = v;
    __syncthreads();
    for (int off = 1; off < 512; off <<= 1) {
        int a = (t >= off) ? sh[t - off] : 0;
        __syncthreads();
        sh[t] += a;
        __syncthreads();
    }
    if (t < NBLKA) hist[t * NB + b] = sh[t] - v;
    if (t == 511) atomicExch(&bhist[b], sh[511]);
    __syncthreads();
    if (t == 0) {
        __threadfence();
        amLast = (atomicAdd(ticket, 1) == NB - 1) ? 1 : 0;
    }
    __syncthreads();
    if (amLast) {
        int v2 = (t < NB) ? atomicAdd(&bhist[t], 0) : 0;
        __syncthreads();
        sh[t] = v2;
        __syncthreads();
        for (int off = 1; off < 512; off <<= 1) {
            int a = (t >= off) ? sh[t - off] : 0;
            __syncthreads();
            sh[t] += a;
            __syncthreads();
        }
        if (t < NB) bbase[t] = sh[t] - v2;
        if (t == NB - 1) bbase[NB] = sh[t];
    }
}

// scatter only: bases are precomputed (bbase + per-block prefix), LDS atomics
// give within-chunk offsets. No global atomics at all.
__global__ __launch_bounds__(256) void k_pairs(const int* __restrict__ src,
                                               const int* __restrict__ dst,
                                               const int* __restrict__ hist,
                                               const int* __restrict__ bbase,
                                               int2* __restrict__ ebuf) {
    __shared__ int lh[NB];
    __shared__ int lbase[NB];
    int t = threadIdx.x;
    for (int i = t; i < NB; i += 256) {
        lh[i] = 0;
        lbase[i] = bbase[i] + hist[blockIdx.x * NB + i];
    }
    __syncthreads();
    int e0 = blockIdx.x * EPB;
    int e1 = min(e0 + EPB, NE);
    for (int e = e0 + t; e < e1; e += 256) {
        int s = src[e], d = dst[e];
        int bk = d >> 8;
        int off = atomicAdd(&lh[bk], 1);
        ebuf[lbase[bk] + off] = make_int2(s, d);
    }
}

// col stores BYTE offsets (src*DF) for gather fp8 table (128 B rows)
__global__ __launch_bounds__(256) void k_build(const int2* __restrict__ ebuf,
                                               const int* __restrict__ bbase,
                                               int* __restrict__ rowptr,
                                               float* __restrict__ dinv,
                                               int* __restrict__ col) {
    __shared__ int deg[256];
    __shared__ int lst[256];
    int b = blockIdx.x, t = threadIdx.x;
    int n0 = b << 8;
    int node = n0 + t;
    deg[t] = 0;
    __syncthreads();
    int e0 = bbase[b], e1 = bbase[b + 1];
    for (int e = e0 + t; e < e1; e += 256) atomicAdd(&deg[ebuf[e].y - n0], 1);
    __syncthreads();
    int v = deg[t];
    lst[t] = v;
    __syncthreads();
    for (int off = 1; off < 256; off <<= 1) {
        int a = (t >= off) ? lst[t - off] : 0;
        __syncthreads();
        lst[t] += a;
        __syncthreads();
    }
    int mystart = e0 + lst[t] - v;
    if (node < NN) {
        rowptr[node] = mystart;
        dinv[node] = rsqrtf((float)(v + 1));  // +1 self-loop
    }
    if (b == NB - 1 && t == 255) rowptr[NN] = e1;
    lst[t] = mystart;
    __syncthreads();
    for (int e = e0 + t; e < e1; e += 256) {
        int2 pr = ebuf[e];
        int p = atomicAdd(&lst[pr.y - n0], 1);
        col[p] = pr.x * DF;
    }
}

// ---------------- per-layer compute ----------------

// shared MFMA+scale+fp8-pack core for the gemm kernels
__device__ __forceinline__ void gemm_core(const short8* af,
                                          const unsigned short* __restrict__ Wb,
                                          const float* __restrict__ dinv,
                                          int lane, int lm, int orow,
                                          unsigned char* __restrict__ fs8) {
    float dv[4];
#pragma unroll
    for (int j = 0; j < 4; j++) dv[j] = (orow + j < NN) ? dinv[orow + j] : 0.f;

    float res[4][8];
#pragma unroll
    for (int tt = 0; tt < 8; tt++) {
        floatx4 acc = {0.f, 0.f, 0.f, 0.f};
        const unsigned short* wp = Wb + ((size_t)(tt * 4) * 64 + lane) * 8;
        acc = __builtin_amdgcn_mfma_f32_16x16x32_bf16(af[0], *(const short8*)(wp), acc, 0, 0, 0);
        acc = __builtin_amdgcn_mfma_f32_16x16x32_bf16(af[1], *(const short8*)(wp + 512), acc, 0, 0, 0);
        acc = __builtin_amdgcn_mfma_f32_16x16x32_bf16(af[2], *(const short8*)(wp + 1024), acc, 0, 0, 0);
        acc = __builtin_amdgcn_mfma_f32_16x16x32_bf16(af[3], *(const short8*)(wp + 1536), acc, 0, 0, 0);
#pragma unroll
        for (int j = 0; j < 4; j++) res[j][tt] = acc[j] * dv[j];
    }

#pragma unroll
    for (int g = 0; g < 2; g++) {
#pragma unroll
        for (int j = 0; j < 4; j++) {
            int r = orow + j;
            if (r >= NN) continue;
            unsigned int w8 = __builtin_amdgcn_cvt_pk_fp8_f32(res[j][g * 4 + 0], res[j][g * 4 + 1], 0, false);
            w8 = __builtin_amdgcn_cvt_pk_fp8_f32(res[j][g * 4 + 2], res[j][g * 4 + 3], w8, true);
            *(unsigned int*)&fs8[(size_t)r * DF + g * 64 + lm * 4] = w8;
        }
    }
}

// layer-1 gemm: reads x (f32) directly, converts to bf16 in-register.
// Wb1 is prepared in logical k-order, so no permutation gather is needed.
__global__ __launch_bounds__(256) void k_gemm1(const float* __restrict__ X,
                                               const unsigned short* __restrict__ Wb,
                                               const float* __restrict__ dinv,
                                               unsigned char* __restrict__ fs8) {
    int t = threadIdx.x;
    int wave = t >> 6, l = t & 63;
    int r0 = blockIdx.x * 64 + wave * 16;
    int lm = l & 15, q = l >> 4;

    int arow = r0 + lm;
    if (arow >= NN) arow = NN - 1;
    const float* xrow = X + (size_t)arow * DF + q * 8;
    short8 af[4];
#pragma unroll
    for (int s = 0; s < 4; s++) {
        float4 f0 = *(const float4*)(xrow + s * 32);
        float4 f1 = *(const float4*)(xrow + s * 32 + 4);
        unsigned short o[8] = {f2bf(f0.x), f2bf(f0.y), f2bf(f0.z), f2bf(f0.w),
                               f2bf(f1.x), f2bf(f1.y), f2bf(f1.z), f2bf(f1.w)};
        af[s] = *(short8*)o;
    }
    gemm_core(af, Wb, dinv, l, lm, r0 + q * 4, fs8);
}

// layers 2-3 gemm: reads bf16 activations (physical layout), Wb in phi k-order.
__global__ __launch_bounds__(256) void k_gemm(const unsigned short* __restrict__ X,
                                              const unsigned short* __restrict__ Wb,
                                              const float* __restrict__ dinv,
                                              unsigned char* __restrict__ fs8) {
    int t = threadIdx.x;
    int wave = t >> 6, l = t & 63;
    int r0 = blockIdx.x * 64 + wave * 16;
    int lm = l & 15, q = l >> 4;

    int arow = r0 + lm;
    if (arow >= NN) arow = NN - 1;
    const unsigned short* xrow = X + (size_t)arow * DF + q * 8;
    short8 af[4];
#pragma unroll
    for (int s = 0; s < 4; s++) af[s] = *(const short8*)(xrow + s * 32);
    gemm_core(af, Wb, dinv, l, lm, r0 + q * 4, fs8);
}

// aggregation core: one 16-lane sub aggregates node n. Zero-row trick makes
// all accumulates unconditional; deg<=16 issues all gathers in one flight.
__device__ __forceinline__ void agg_node(const unsigned char* __restrict__ fs8,
                                         const int* __restrict__ colb,
                                         int n, int foff, int e0, int e1,
                                         float dvn, const float* bias,
                                         float* o) {
    floatx2 acc0 = {0.f, 0.f}, acc1 = {0.f, 0.f}, acc2 = {0.f, 0.f}, acc3 = {0.f, 0.f};
    int deg = e1 - e0;
    if (deg <= 16) {
        int cb[16];
#pragma unroll
        for (int k = 0; k < 16; k++) {
            int idx = e0 + k;
            int cv = colb[min(idx, e1 - 1)];
            cb[k] = (idx < e1) ? cv : ZOFF;
        }
        uint2 vv[16];
#pragma unroll
        for (int k = 0; k < 16; k++) vv[k] = *(const uint2*)&fs8[(size_t)cb[k] + foff];
#pragma unroll
        for (int k = 0; k < 16; k++) {
            acc0 += __builtin_amdgcn_cvt_pk_f32_fp8(vv[k].x, false);
            acc1 += __builtin_amdgcn_cvt_pk_f32_fp8(vv[k].x, true);
            acc2 += __builtin_amdgcn_cvt_pk_f32_fp8(vv[k].y, false);
            acc3 += __builtin_amdgcn_cvt_pk_f32_fp8(vv[k].y, true);
        }
    } else {
        for (int base = e0; base < e1; base += 8) {
            int cb[8];
#pragma unroll
            for (int k = 0; k < 8; k++) {
                int idx = base + k;
                int cv = colb[min(idx, e1 - 1)];
                cb[k] = (idx < e1) ? cv : ZOFF;
            }
            uint2 vv[8];
#pragma unroll
            for (int k = 0; k < 8; k++) vv[k] = *(const uint2*)&fs8[(size_t)cb[k] + foff];
#pragma unroll
            for (int k = 0; k < 8; k++) {
                acc0 += __builtin_amdgcn_cvt_pk_f32_fp8(vv[k].x, false);
                acc1 += __builtin_amdgcn_cvt_pk_f32_fp8(vv[k].x, true);
                acc2 += __builtin_amdgcn_cvt_pk_f32_fp8(vv[k].y, false);
                acc3 += __builtin_amdgcn_cvt_pk_f32_fp8(vv[k].y, true);
            }
        }
    }
    // self-loop row (fp8, dinv[src] already folded in)
    uint2 sv = *(const uint2*)&fs8[(size_t)n * DF + foff];
    acc0 += __builtin_amdgcn_cvt_pk_f32_fp8(sv.x, false);
    acc1 += __builtin_amdgcn_cvt_pk_f32_fp8(sv.x, true);
    acc2 += __builtin_amdgcn_cvt_pk_f32_fp8(sv.y, false);
    acc3 += __builtin_amdgcn_cvt_pk_f32_fp8(sv.y, true);

    float a[8] = {acc0.x, acc0.y, acc1.x, acc1.y, acc2.x, acc2.y, acc3.x, acc3.y};
#pragma unroll
    for (int j = 0; j < 8; j++) o[j] = fmaxf(dvn * a[j] + bias[j], 0.f);
}

// 4 nodes per wave, each 16-lane sub owns one node. No cross-sub reduction,
// full-lane epilogue, wave stores 4 contiguous rows (1 KB coalesced).
__global__ __launch_bounds__(256) void k_agg(const unsigned char* __restrict__ fs8,
                                             const int* __restrict__ colb,
                                             const int* __restrict__ rowptr,
                                             const float* __restrict__ dinv,
                                             const float* __restrict__ b,
                                             unsigned short* __restrict__ out) {
    int w = (int)((blockIdx.x * (size_t)blockDim.x + threadIdx.x) >> 6);
    int lane = threadIdx.x & 63;
    int sub = lane >> 4;
    int fo = lane & 15;
    int foff = fo * 8;
    int n = w * 4 + sub;

    float bias[8];
#pragma unroll
    for (int j = 0; j < 8; j++) bias[j] = b[phi(foff + j)];
    float dvn = dinv[n];
    int e0 = rowptr[n], e1 = rowptr[n + 1];

    float o[8];
    agg_node(fs8, colb, n, foff, e0, e1, dvn, bias, o);

    uint4 pk;
    pk.x = (unsigned int)f2bf(o[0]) | ((unsigned int)f2bf(o[1]) << 16);
    pk.y = (unsigned int)f2bf(o[2]) | ((unsigned int)f2bf(o[3]) << 16);
    pk.z = (unsigned int)f2bf(o[4]) | ((unsigned int)f2bf(o[5]) << 16);
    pk.w = (unsigned int)f2bf(o[6]) | ((unsigned int)f2bf(o[7]) << 16);
    *(uint4*)&out[(size_t)n * DF + foff] = pk;
}

// ---------------- pooling + FC ----------------

__global__ __launch_bounds__(256) void k_poolA(const unsigned short* __restrict__ h,
                                               const int* __restrict__ gstart,
                                               float* __restrict__ part) {
    __shared__ float2 red[256];
    int g = blockIdx.x >> 3, c = blockIdx.x & 7;
    int s = gstart[g], e = gstart[g + 1];
    int len = e - s;
    int cs = s + (int)(((long long)len * c) >> 3);
    int ce = s + (int)(((long long)len * (c + 1)) >> 3);
    int t = threadIdx.x;
    int fp = t & 63;
    int rs = t >> 6;
    float2 acc = make_float2(0.f, 0.f);
    for (int n = cs + rs; n < ce; n += 4) {
        unsigned int v = *(const unsigned int*)&h[(size_t)n * DF + fp * 2];
        acc.x += bf2f_lo(v);
        acc.y += bf2f_hi(v);
    }
    red[t] = acc;
    __syncthreads();
    if (rs == 0) {
        float2 a0 = red[fp], a1 = red[fp + 64], a2 = red[fp + 128], a3 = red[fp + 192];
        float2 o;
        o.x = (a0.x + a1.x) + (a2.x + a3.x);
        o.y = (a0.y + a1.y) + (a2.y + a3.y);
        *(float2*)&part[(size_t)blockIdx.x * DF + fp * 2] = o;
    }
}

// phase B + FC fused: reduce partials -> pooled (LDS, un-permuted) -> FC
__global__ __launch_bounds__(128) void k_poolfc(const float* __restrict__ part,
                                                const int* __restrict__ gstart,
                                                const float* __restrict__ Wfc,
                                                const float* __restrict__ bfc,
                                                float* __restrict__ out) {
    __shared__ float pl[DF];
    int g = blockIdx.x;
    int f = threadIdx.x;
    float s = 0.f;
#pragma unroll
    for (int c = 0; c < PCH; c++) s += part[(size_t)(g * PCH + c) * DF + f];
    int cnt = gstart[g + 1] - gstart[g];
    pl[phi(f)] = s / (float)max(cnt, 1);
    __syncthreads();
    if (f < DOUT) {
        float acc = bfc[f];
        for (int k = 0; k < DF; k++) acc += pl[k] * Wfc[k * DOUT + f];
        out[g * DOUT + f] = acc;
    }
}

// ---------------- launch ----------------

extern "C" void kernel_launch(void* const* d_in, const int* in_sizes, int n_in,
                              void* d_out, int out_size, void* d_ws, size_t ws_size,
                              hipStream_t stream) {
    const float* x     = (const float*)d_in[0];
    const int*   ei    = (const int*)d_in[1];
    const int*   batch = (const int*)d_in[2];
    const float* W1 = (const float*)d_in[3];
    const float* b1 = (const float*)d_in[4];
    const float* W2 = (const float*)d_in[5];
    const float* b2 = (const float*)d_in[6];
    const float* W3 = (const float*)d_in[7];
    const float* b3 = (const float*)d_in[8];
    const float* Wfc = (const float*)d_in[9];
    const float* bfc = (const float*)d_in[10];
    float* out = (float*)d_out;

    char* p = (char*)d_ws;
    unsigned short* ob = (unsigned short*)p;  p += (size_t)NN * DF * sizeof(short);
    unsigned char*  fs8 = (unsigned char*)p;  p += (size_t)NN * DF + 256;  // + zero row
    unsigned short* Wb1 = (unsigned short*)p; p += 16384 * sizeof(short);
    unsigned short* Wb2 = (unsigned short*)p; p += 16384 * sizeof(short);
    unsigned short* Wb3 = (unsigned short*)p; p += 16384 * sizeof(short);
    float* dinv = (float*)p;           p += (size_t)NN * sizeof(float);
    int* rowptr = (int*)p;             p += (size_t)(NN + 4) * sizeof(int);
    int* col    = (int*)p;             p += (size_t)NE * sizeof(int);
    int2* ebuf  = (int2*)p;            p += (size_t)NE * sizeof(int2);
    int* bhist  = (int*)p;             p += (size_t)(NB + 4) * sizeof(int);
    int* bbase  = (int*)p;             p += (size_t)(NB + 4) * sizeof(int);
    int* hist   = (int*)p;             p += (size_t)NBLKA * NB * sizeof(int);
    int* gstart = (int*)p;             p += (size_t)(NG + 4) * sizeof(int);
    int* ticket = (int*)p;             p += 4 * sizeof(int);
    float* part = (float*)p;           p += (size_t)NG * PCH * DF * sizeof(float);

    const int* e_src = ei;
    const int* e_dst = ei + NE;

    // init (hist + bounds + zero-row + 3x prepw), merged scans, scatter, CSR build
    k_init<<<NBLKA + 26, 256, 0, stream>>>(e_dst, hist, batch, gstart, fs8, ticket,
                                           W1, W2, W3, Wb1, Wb2, Wb3);
    k_scan<<<NB, 512, 0, stream>>>(hist, bhist, bbase, ticket);
    k_pairs<<<NBLKA, 256, 0, stream>>>(e_src, e_dst, hist, bbase, ebuf);
    k_build<<<NB, 256, 0, stream>>>(ebuf, bbase, rowptr, dinv, col);

    int ggrid = (NN + 63) / 64;

    // layer 1 (direct f32 x), layers 2-3 (bf16 activations)
    k_gemm1<<<ggrid, 256, 0, stream>>>(x, Wb1, dinv, fs8);
    k_agg<<<NAGB, 256, 0, stream>>>(fs8, col, rowptr, dinv, b1, ob);
    k_gemm<<<ggrid, 256, 0, stream>>>(ob, Wb2, dinv, fs8);
    k_agg<<<NAGB, 256, 0, stream>>>(fs8, col, rowptr, dinv, b2, ob);
    k_gemm<<<ggrid, 256, 0, stream>>>(ob, Wb3, dinv, fs8);
    k_agg<<<NAGB, 256, 0, stream>>>(fs8, col, rowptr, dinv, b3, ob);

    // pool + fc
    k_poolA<<<NG * PCH, 256, 0, stream>>>(ob, gstart, part);
    k_poolfc<<<NG, 128, 0, stream>>>(part, gstart, Wfc, bfc, out);
}

// Round 5
// 331.177 us; speedup vs baseline: 1.0794x; 1.0625x over previous
//
#include <hip/hip_runtime.h>

#define NN 100000
#define NE 1600000
#define DF 128
#define DOUT 64
#define NG 128
#define NB 391      // ceil(NN/256) buckets of 256 nodes
#define EPB 8192    // edges per block in binning passes
#define NBLKA ((NE + EPB - 1) / EPB)  // 196
#define PCH 8       // pool chunks per graph
#define NAGB (NN / 16)  // agg blocks: 16 nodes per block (4 waves x 4 nodes)

typedef short short8 __attribute__((ext_vector_type(8)));
typedef float floatx4 __attribute__((ext_vector_type(4)));
typedef float floatx2 __attribute__((ext_vector_type(2)));

__device__ __forceinline__ unsigned short f2bf(float f) {
    unsigned int b = __float_as_uint(f);
    unsigned int r = (b + 0x7fffu + ((b >> 16) & 1u)) >> 16;
    return (unsigned short)r;
}
__device__ __forceinline__ float bf2f_lo(unsigned int v) { return __uint_as_float(v << 16); }
__device__ __forceinline__ float bf2f_hi(unsigned int v) { return __uint_as_float(v & 0xffff0000u); }

// physical feature index p -> logical feature c.
// p = g*64 + lm*4 + u  (g:0..1, lm:0..15, u:0..3), c = (g*4+u)*16 + lm
__device__ __forceinline__ int phi(int p) {
    return (((p >> 6) << 2) + (p & 3)) * 16 + ((p >> 2) & 15);
}

// ---------------- fused init: dst histogram + graph bounds + prepw ----------------
// blk < NBLKA           : per-chunk dst histogram (plain stores, no global atomics)
// blk == NBLKA          : gstart binary search
// blk == NBLKA+1        : ticket reset
// blk >= NBLKA+2 (24)   : bf16 weight fragments. Wb1 in LOGICAL k-order (layer-1
//                         gemm reads x directly); Wb2/Wb3 in physical (phi) k-order.

__global__ __launch_bounds__(256) void k_init(const int* __restrict__ dst,
                                              int* __restrict__ hist,
                                              const int* __restrict__ batch,
                                              int* __restrict__ gstart,
                                              int* __restrict__ ticket,
                                              const float* __restrict__ W1,
                                              const float* __restrict__ W2,
                                              const float* __restrict__ W3,
                                              unsigned short* __restrict__ O1,
                                              unsigned short* __restrict__ O2,
                                              unsigned short* __restrict__ O3) {
    __shared__ int lh[NB];
    int blk = blockIdx.x;
    int t = threadIdx.x;
    if (blk < NBLKA) {
        for (int i = t; i < NB; i += 256) lh[i] = 0;
        __syncthreads();
        int e0 = blk * EPB;
        int e1 = min(e0 + EPB, NE);
        for (int e = e0 + t; e < e1; e += 256) atomicAdd(&lh[dst[e] >> 8], 1);
        __syncthreads();
        for (int i = t; i < NB; i += 256) hist[blk * NB + i] = lh[i];
    } else if (blk == NBLKA) {
        int g = t;
        if (g > NG) return;
        int lo = 0, hi = NN;
        while (lo < hi) {
            int mid = (lo + hi) >> 1;
            if (batch[mid] < g) lo = mid + 1; else hi = mid;
        }
        gstart[g] = lo;
    } else if (blk == NBLKA + 1) {
        if (t == 0) *ticket = 0;
    } else {
        int bb = blk - (NBLKA + 2);
        const float* W = (bb >= 16) ? W3 : (bb >= 8) ? W2 : W1;
        unsigned short* O = (bb >= 16) ? O3 : (bb >= 8) ? O2 : O1;
        bool logical = (bb < 8);
        int idx = (bb & 7) * 256 + t;
        int l = idx & 63;
        int s = (idx >> 6) & 3;
        int tt = idx >> 8;
        int k0 = s * 32 + (l >> 4) * 8;
        int c = tt * 16 + (l & 15);
        unsigned short o[8];
#pragma unroll
        for (int j = 0; j < 8; j++) {
            int kk = logical ? (k0 + j) : phi(k0 + j);
            o[j] = f2bf(W[kk * DF + c]);
        }
        *(short8*)&O[idx * 8] = *(short8*)o;
    }
}

// ---------------- merged hscan + bscan (last-block ticket) ----------------
// Per bucket b: exclusive-scan hist[*][b] over the 196 chunk blocks (in place),
// bucket total -> bhist[b] (atomicExch, device scope). Last block to finish
// scans bhist into bbase. Cross-block values only via atomics (XCD-L2 safe).

__global__ __launch_bounds__(512) void k_scan(int* __restrict__ hist,
                                              int* __restrict__ bhist,
                                              int* __restrict__ bbase,
                                              int* __restrict__ ticket) {
    __shared__ int sh[512];
    __shared__ int amLast;
    int b = blockIdx.x, t = threadIdx.x;
    int v = (t < NBLKA) ? hist[t * NB + b] : 0;
    sh[t] = v;
    __syncthreads();
    for (int off = 1; off < 512; off <<= 1) {
        int a = (t >= off) ? sh[t - off] : 0;
        __syncthreads();
        sh[t] += a;
        __syncthreads();
    }
    if (t < NBLKA) hist[t * NB + b] = sh[t] - v;
    if (t == 511) atomicExch(&bhist[b], sh[511]);
    __syncthreads();
    if (t == 0) {
        __threadfence();
        amLast = (atomicAdd(ticket, 1) == NB - 1) ? 1 : 0;
    }
    __syncthreads();
    if (amLast) {
        int v2 = (t < NB) ? atomicAdd(&bhist[t], 0) : 0;
        __syncthreads();
        sh[t] = v2;
        __syncthreads();
        for (int off = 1; off < 512; off <<= 1) {
            int a = (t >= off) ? sh[t - off] : 0;
            __syncthreads();
            sh[t] += a;
            __syncthreads();
        }
        if (t < NB) bbase[t] = sh[t] - v2;
        if (t == NB - 1) bbase[NB] = sh[t];
    }
}

// scatter only: bases are precomputed (bbase + per-block prefix), LDS atomics
// give within-chunk offsets. No global atomics at all.
__global__ __launch_bounds__(256) void k_pairs(const int* __restrict__ src,
                                               const int* __restrict__ dst,
                                               const int* __restrict__ hist,
                                               const int* __restrict__ bbase,
                                               int2* __restrict__ ebuf) {
    __shared__ int lh[NB];
    __shared__ int lbase[NB];
    int t = threadIdx.x;
    for (int i = t; i < NB; i += 256) {
        lh[i] = 0;
        lbase[i] = bbase[i] + hist[blockIdx.x * NB + i];
    }
    __syncthreads();
    int e0 = blockIdx.x * EPB;
    int e1 = min(e0 + EPB, NE);
    for (int e = e0 + t; e < e1; e += 256) {
        int s = src[e], d = dst[e];
        int bk = d >> 8;
        int off = atomicAdd(&lh[bk], 1);
        ebuf[lbase[bk] + off] = make_int2(s, d);
    }
}

// col stores BYTE offsets (src*DF) for gather fp8 table (128 B rows)
__global__ __launch_bounds__(256) void k_build(const int2* __restrict__ ebuf,
                                               const int* __restrict__ bbase,
                                               int* __restrict__ rowptr,
                                               float* __restrict__ dinv,
                                               int* __restrict__ col) {
    __shared__ int deg[256];
    __shared__ int lst[256];
    int b = blockIdx.x, t = threadIdx.x;
    int n0 = b << 8;
    int node = n0 + t;
    deg[t] = 0;
    __syncthreads();
    int e0 = bbase[b], e1 = bbase[b + 1];
    for (int e = e0 + t; e < e1; e += 256) atomicAdd(&deg[ebuf[e].y - n0], 1);
    __syncthreads();
    int v = deg[t];
    lst[t] = v;
    __syncthreads();
    for (int off = 1; off < 256; off <<= 1) {
        int a = (t >= off) ? lst[t - off] : 0;
        __syncthreads();
        lst[t] += a;
        __syncthreads();
    }
    int mystart = e0 + lst[t] - v;
    if (node < NN) {
        rowptr[node] = mystart;
        dinv[node] = rsqrtf((float)(v + 1));  // +1 self-loop
    }
    if (b == NB - 1 && t == 255) rowptr[NN] = e1;
    lst[t] = mystart;
    __syncthreads();
    for (int e = e0 + t; e < e1; e += 256) {
        int2 pr = ebuf[e];
        int p = atomicAdd(&lst[pr.y - n0], 1);
        col[p] = pr.x * DF;
    }
}

// ---------------- per-layer compute ----------------

// shared MFMA+scale+fp8-pack core for the gemm kernels
__device__ __forceinline__ void gemm_core(const short8* af,
                                          const unsigned short* __restrict__ Wb,
                                          const float* __restrict__ dinv,
                                          int lane, int lm, int orow,
                                          unsigned char* __restrict__ fs8) {
    float dv[4];
#pragma unroll
    for (int j = 0; j < 4; j++) dv[j] = (orow + j < NN) ? dinv[orow + j] : 0.f;

    float res[4][8];
#pragma unroll
    for (int tt = 0; tt < 8; tt++) {
        floatx4 acc = {0.f, 0.f, 0.f, 0.f};
        const unsigned short* wp = Wb + ((size_t)(tt * 4) * 64 + lane) * 8;
        acc = __builtin_amdgcn_mfma_f32_16x16x32_bf16(af[0], *(const short8*)(wp), acc, 0, 0, 0);
        acc = __builtin_amdgcn_mfma_f32_16x16x32_bf16(af[1], *(const short8*)(wp + 512), acc, 0, 0, 0);
        acc = __builtin_amdgcn_mfma_f32_16x16x32_bf16(af[2], *(const short8*)(wp + 1024), acc, 0, 0, 0);
        acc = __builtin_amdgcn_mfma_f32_16x16x32_bf16(af[3], *(const short8*)(wp + 1536), acc, 0, 0, 0);
#pragma unroll
        for (int j = 0; j < 4; j++) res[j][tt] = acc[j] * dv[j];
    }

#pragma unroll
    for (int g = 0; g < 2; g++) {
#pragma unroll
        for (int j = 0; j < 4; j++) {
            int r = orow + j;
            if (r >= NN) continue;
            unsigned int w8 = __builtin_amdgcn_cvt_pk_fp8_f32(res[j][g * 4 + 0], res[j][g * 4 + 1], 0, false);
            w8 = __builtin_amdgcn_cvt_pk_fp8_f32(res[j][g * 4 + 2], res[j][g * 4 + 3], w8, true);
            *(unsigned int*)&fs8[(size_t)r * DF + g * 64 + lm * 4] = w8;
        }
    }
}

// layer-1 gemm: reads x (f32) directly, converts to bf16 in-register.
// Wb1 is prepared in logical k-order, so no permutation gather is needed.
__global__ __launch_bounds__(256) void k_gemm1(const float* __restrict__ X,
                                               const unsigned short* __restrict__ Wb,
                                               const float* __restrict__ dinv,
                                               unsigned char* __restrict__ fs8) {
    int t = threadIdx.x;
    int wave = t >> 6, l = t & 63;
    int r0 = blockIdx.x * 64 + wave * 16;
    int lm = l & 15, q = l >> 4;

    int arow = r0 + lm;
    if (arow >= NN) arow = NN - 1;
    const float* xrow = X + (size_t)arow * DF + q * 8;
    short8 af[4];
#pragma unroll
    for (int s = 0; s < 4; s++) {
        float4 f0 = *(const float4*)(xrow + s * 32);
        float4 f1 = *(const float4*)(xrow + s * 32 + 4);
        unsigned short o[8] = {f2bf(f0.x), f2bf(f0.y), f2bf(f0.z), f2bf(f0.w),
                               f2bf(f1.x), f2bf(f1.y), f2bf(f1.z), f2bf(f1.w)};
        af[s] = *(short8*)o;
    }
    gemm_core(af, Wb, dinv, l, lm, r0 + q * 4, fs8);
}

// layers 2-3 gemm: reads bf16 activations (physical layout), Wb in phi k-order.
__global__ __launch_bounds__(256) void k_gemm(const unsigned short* __restrict__ X,
                                              const unsigned short* __restrict__ Wb,
                                              const float* __restrict__ dinv,
                                              unsigned char* __restrict__ fs8) {
    int t = threadIdx.x;
    int wave = t >> 6, l = t & 63;
    int r0 = blockIdx.x * 64 + wave * 16;
    int lm = l & 15, q = l >> 4;

    int arow = r0 + lm;
    if (arow >= NN) arow = NN - 1;
    const unsigned short* xrow = X + (size_t)arow * DF + q * 8;
    short8 af[4];
#pragma unroll
    for (int s = 0; s < 4; s++) af[s] = *(const short8*)(xrow + s * 32);
    gemm_core(af, Wb, dinv, l, lm, r0 + q * 4, fs8);
}

// aggregation core (round-2 shape: 8-deep batches, predicated accumulate;
// VGPR ~32, proven ≤41 µs — the 16-deep single-flight variant cost occupancy).
__device__ __forceinline__ void agg_node(const unsigned char* __restrict__ fs8,
                                         const int* __restrict__ colb,
                                         int n, int foff, int e0, int e1,
                                         float dvn, const float* bias,
                                         float* o) {
    floatx2 acc0 = {0.f, 0.f}, acc1 = {0.f, 0.f}, acc2 = {0.f, 0.f}, acc3 = {0.f, 0.f};
    for (int base = e0; base < e1; base += 8) {
        int cb[8];
#pragma unroll
        for (int k = 0; k < 8; k++) cb[k] = colb[min(base + k, e1 - 1)];
        uint2 vv[8];
#pragma unroll
        for (int k = 0; k < 8; k++) vv[k] = *(const uint2*)&fs8[(size_t)cb[k] + foff];
#pragma unroll
        for (int k = 0; k < 8; k++) {
            if (base + k < e1) {
                acc0 += __builtin_amdgcn_cvt_pk_f32_fp8(vv[k].x, false);
                acc1 += __builtin_amdgcn_cvt_pk_f32_fp8(vv[k].x, true);
                acc2 += __builtin_amdgcn_cvt_pk_f32_fp8(vv[k].y, false);
                acc3 += __builtin_amdgcn_cvt_pk_f32_fp8(vv[k].y, true);
            }
        }
    }
    // self-loop row (fp8, dinv[src] already folded in)
    uint2 sv = *(const uint2*)&fs8[(size_t)n * DF + foff];
    acc0 += __builtin_amdgcn_cvt_pk_f32_fp8(sv.x, false);
    acc1 += __builtin_amdgcn_cvt_pk_f32_fp8(sv.x, true);
    acc2 += __builtin_amdgcn_cvt_pk_f32_fp8(sv.y, false);
    acc3 += __builtin_amdgcn_cvt_pk_f32_fp8(sv.y, true);

    float a[8] = {acc0.x, acc0.y, acc1.x, acc1.y, acc2.x, acc2.y, acc3.x, acc3.y};
#pragma unroll
    for (int j = 0; j < 8; j++) o[j] = fmaxf(dvn * a[j] + bias[j], 0.f);
}

// 4 nodes per wave, each 16-lane sub owns one node. No cross-sub reduction,
// full-lane epilogue, wave stores 4 contiguous rows (1 KB coalesced).
__global__ __launch_bounds__(256) void k_agg(const unsigned char* __restrict__ fs8,
                                             const int* __restrict__ colb,
                                             const int* __restrict__ rowptr,
                                             const float* __restrict__ dinv,
                                             const float* __restrict__ b,
                                             unsigned short* __restrict__ out) {
    int w = (int)((blockIdx.x * (size_t)blockDim.x + threadIdx.x) >> 6);
    int lane = threadIdx.x & 63;
    int sub = lane >> 4;
    int fo = lane & 15;
    int foff = fo * 8;
    int n = w * 4 + sub;

    float bias[8];
#pragma unroll
    for (int j = 0; j < 8; j++) bias[j] = b[phi(foff + j)];
    float dvn = dinv[n];
    int e0 = rowptr[n], e1 = rowptr[n + 1];

    float o[8];
    agg_node(fs8, colb, n, foff, e0, e1, dvn, bias, o);

    uint4 pk;
    pk.x = (unsigned int)f2bf(o[0]) | ((unsigned int)f2bf(o[1]) << 16);
    pk.y = (unsigned int)f2bf(o[2]) | ((unsigned int)f2bf(o[3]) << 16);
    pk.z = (unsigned int)f2bf(o[4]) | ((unsigned int)f2bf(o[5]) << 16);
    pk.w = (unsigned int)f2bf(o[6]) | ((unsigned int)f2bf(o[7]) << 16);
    *(uint4*)&out[(size_t)n * DF + foff] = pk;
}

// ---------------- pooling + FC ----------------

__global__ __launch_bounds__(256) void k_poolA(const unsigned short* __restrict__ h,
                                               const int* __restrict__ gstart,
                                               float* __restrict__ part) {
    __shared__ float2 red[256];
    int g = blockIdx.x >> 3, c = blockIdx.x & 7;
    int s = gstart[g], e = gstart[g + 1];
    int len = e - s;
    int cs = s + (int)(((long long)len * c) >> 3);
    int ce = s + (int)(((long long)len * (c + 1)) >> 3);
    int t = threadIdx.x;
    int fp = t & 63;
    int rs = t >> 6;
    float2 acc = make_float2(0.f, 0.f);
    for (int n = cs + rs; n < ce; n += 4) {
        unsigned int v = *(const unsigned int*)&h[(size_t)n * DF + fp * 2];
        acc.x += bf2f_lo(v);
        acc.y += bf2f_hi(v);
    }
    red[t] = acc;
    __syncthreads();
    if (rs == 0) {
        float2 a0 = red[fp], a1 = red[fp + 64], a2 = red[fp + 128], a3 = red[fp + 192];
        float2 o;
        o.x = (a0.x + a1.x) + (a2.x + a3.x);
        o.y = (a0.y + a1.y) + (a2.y + a3.y);
        *(float2*)&part[(size_t)blockIdx.x * DF + fp * 2] = o;
    }
}

// phase B + FC fused: reduce partials -> pooled (LDS, un-permuted) -> FC
__global__ __launch_bounds__(128) void k_poolfc(const float* __restrict__ part,
                                                const int* __restrict__ gstart,
                                                const float* __restrict__ Wfc,
                                                const float* __restrict__ bfc,
                                                float* __restrict__ out) {
    __shared__ float pl[DF];
    int g = blockIdx.x;
    int f = threadIdx.x;
    float s = 0.f;
#pragma unroll
    for (int c = 0; c < PCH; c++) s += part[(size_t)(g * PCH + c) * DF + f];
    int cnt = gstart[g + 1] - gstart[g];
    pl[phi(f)] = s / (float)max(cnt, 1);
    __syncthreads();
    if (f < DOUT) {
        float acc = bfc[f];
        for (int k = 0; k < DF; k++) acc += pl[k] * Wfc[k * DOUT + f];
        out[g * DOUT + f] = acc;
    }
}

// ---------------- launch ----------------

extern "C" void kernel_launch(void* const* d_in, const int* in_sizes, int n_in,
                              void* d_out, int out_size, void* d_ws, size_t ws_size,
                              hipStream_t stream) {
    const float* x     = (const float*)d_in[0];
    const int*   ei    = (const int*)d_in[1];
    const int*   batch = (const int*)d_in[2];
    const float* W1 = (const float*)d_in[3];
    const float* b1 = (const float*)d_in[4];
    const float* W2 = (const float*)d_in[5];
    const float* b2 = (const float*)d_in[6];
    const float* W3 = (const float*)d_in[7];
    const float* b3 = (const float*)d_in[8];
    const float* Wfc = (const float*)d_in[9];
    const float* bfc = (const float*)d_in[10];
    float* out = (float*)d_out;

    char* p = (char*)d_ws;
    unsigned short* ob = (unsigned short*)p;  p += (size_t)NN * DF * sizeof(short);
    unsigned char*  fs8 = (unsigned char*)p;  p += (size_t)NN * DF + 256;
    unsigned short* Wb1 = (unsigned short*)p; p += 16384 * sizeof(short);
    unsigned short* Wb2 = (unsigned short*)p; p += 16384 * sizeof(short);
    unsigned short* Wb3 = (unsigned short*)p; p += 16384 * sizeof(short);
    float* dinv = (float*)p;           p += (size_t)NN * sizeof(float);
    int* rowptr = (int*)p;             p += (size_t)(NN + 4) * sizeof(int);
    int* col    = (int*)p;             p += (size_t)NE * sizeof(int);
    int2* ebuf  = (int2*)p;            p += (size_t)NE * sizeof(int2);
    int* bhist  = (int*)p;             p += (size_t)(NB + 4) * sizeof(int);
    int* bbase  = (int*)p;             p += (size_t)(NB + 4) * sizeof(int);
    int* hist   = (int*)p;             p += (size_t)NBLKA * NB * sizeof(int);
    int* gstart = (int*)p;             p += (size_t)(NG + 4) * sizeof(int);
    int* ticket = (int*)p;             p += 4 * sizeof(int);
    float* part = (float*)p;           p += (size_t)NG * PCH * DF * sizeof(float);

    const int* e_src = ei;
    const int* e_dst = ei + NE;

    // init (hist + bounds + ticket + 3x prepw), merged scans, scatter, CSR build
    k_init<<<NBLKA + 26, 256, 0, stream>>>(e_dst, hist, batch, gstart, ticket,
                                           W1, W2, W3, Wb1, Wb2, Wb3);
    k_scan<<<NB, 512, 0, stream>>>(hist, bhist, bbase, ticket);
    k_pairs<<<NBLKA, 256, 0, stream>>>(e_src, e_dst, hist, bbase, ebuf);
    k_build<<<NB, 256, 0, stream>>>(ebuf, bbase, rowptr, dinv, col);

    int ggrid = (NN + 63) / 64;

    // layer 1 (direct f32 x), layers 2-3 (bf16 activations)
    k_gemm1<<<ggrid, 256, 0, stream>>>(x, Wb1, dinv, fs8);
    k_agg<<<NAGB, 256, 0, stream>>>(fs8, col, rowptr, dinv, b1, ob);
    k_gemm<<<ggrid, 256, 0, stream>>>(ob, Wb2, dinv, fs8);
    k_agg<<<NAGB, 256, 0, stream>>>(fs8, col, rowptr, dinv, b2, ob);
    k_gemm<<<ggrid, 256, 0, stream>>>(ob, Wb3, dinv, fs8);
    k_agg<<<NAGB, 256, 0, stream>>>(fs8, col, rowptr, dinv, b3, ob);

    // pool + fc
    k_poolA<<<NG * PCH, 256, 0, stream>>>(ob, gstart, part);
    k_poolfc<<<NG, 128, 0, stream>>>(part, gstart, Wfc, bfc, out);
}

// Round 6
// 329.029 us; speedup vs baseline: 1.0864x; 1.0065x over previous
//
#include <hip/hip_runtime.h>

#define NN 100000
#define NE 1600000
#define DF 128
#define DOUT 64
#define NG 128
#define NB 391      // ceil(NN/256) buckets of 256 nodes
#define EPB 8192    // edges per block in binning passes
#define NBLKA ((NE + EPB - 1) / EPB)  // 196
#define PCH 8       // pool chunks per graph
#define NAGB (NN / 16)  // agg blocks: 16 nodes per block (4 waves x 4 nodes)

typedef short short8 __attribute__((ext_vector_type(8)));
typedef float floatx4 __attribute__((ext_vector_type(4)));
typedef float floatx2 __attribute__((ext_vector_type(2)));

__device__ __forceinline__ unsigned short f2bf(float f) {
    unsigned int b = __float_as_uint(f);
    unsigned int r = (b + 0x7fffu + ((b >> 16) & 1u)) >> 16;
    return (unsigned short)r;
}
__device__ __forceinline__ float bf2f_lo(unsigned int v) { return __uint_as_float(v << 16); }
__device__ __forceinline__ float bf2f_hi(unsigned int v) { return __uint_as_float(v & 0xffff0000u); }

// physical feature index p -> logical feature c.
// p = g*64 + lm*4 + u  (g:0..1, lm:0..15, u:0..3), c = (g*4+u)*16 + lm
__device__ __forceinline__ int phi(int p) {
    return (((p >> 6) << 2) + (p & 3)) * 16 + ((p >> 2) & 15);
}

// ---------------- fused init: dst histogram + graph bounds + prepw ----------------
// blk < NBLKA           : per-chunk dst histogram (plain stores, no global atomics)
// blk == NBLKA          : gstart binary search
// blk == NBLKA+1        : ticket reset + col zero-pad + permuted bias tables
// blk >= NBLKA+2 (24)   : bf16 weight fragments. Wb1 in LOGICAL k-order (layer-1
//                         gemm reads x directly); Wb2/Wb3 in physical (phi) k-order.

__global__ __launch_bounds__(256) void k_init(const int* __restrict__ dst,
                                              int* __restrict__ hist,
                                              const int* __restrict__ batch,
                                              int* __restrict__ gstart,
                                              int* __restrict__ ticket,
                                              int* __restrict__ col,
                                              const float* __restrict__ b1,
                                              const float* __restrict__ b2,
                                              const float* __restrict__ b3,
                                              float* __restrict__ bp,
                                              const float* __restrict__ W1,
                                              const float* __restrict__ W2,
                                              const float* __restrict__ W3,
                                              unsigned short* __restrict__ O1,
                                              unsigned short* __restrict__ O2,
                                              unsigned short* __restrict__ O3) {
    __shared__ int lh[NB];
    int blk = blockIdx.x;
    int t = threadIdx.x;
    if (blk < NBLKA) {
        for (int i = t; i < NB; i += 256) lh[i] = 0;
        __syncthreads();
        int e0 = blk * EPB;
        int e1 = min(e0 + EPB, NE);
        for (int e = e0 + t; e < e1; e += 256) atomicAdd(&lh[dst[e] >> 8], 1);
        __syncthreads();
        for (int i = t; i < NB; i += 256) hist[blk * NB + i] = lh[i];
    } else if (blk == NBLKA) {
        int g = t;
        if (g > NG) return;
        int lo = 0, hi = NN;
        while (lo < hi) {
            int mid = (lo + hi) >> 1;
            if (batch[mid] < g) lo = mid + 1; else hi = mid;
        }
        gstart[g] = lo;
    } else if (blk == NBLKA + 1) {
        if (t == 0) *ticket = 0;
        if (t >= 8 && t < 16) col[NE + (t - 8)] = 0;  // pad: unclamped tail reads land here
        if (t < 128) {
            int c = phi(t);
            bp[t] = b1[c];
            bp[128 + t] = b2[c];
            bp[256 + t] = b3[c];
        }
    } else {
        int bb = blk - (NBLKA + 2);
        const float* W = (bb >= 16) ? W3 : (bb >= 8) ? W2 : W1;
        unsigned short* O = (bb >= 16) ? O3 : (bb >= 8) ? O2 : O1;
        bool logical = (bb < 8);
        int idx = (bb & 7) * 256 + t;
        int l = idx & 63;
        int s = (idx >> 6) & 3;
        int tt = idx >> 8;
        int k0 = s * 32 + (l >> 4) * 8;
        int c = tt * 16 + (l & 15);
        unsigned short o[8];
#pragma unroll
        for (int j = 0; j < 8; j++) {
            int kk = logical ? (k0 + j) : phi(k0 + j);
            o[j] = f2bf(W[kk * DF + c]);
        }
        *(short8*)&O[idx * 8] = *(short8*)o;
    }
}

// ---------------- merged hscan + bscan (last-block ticket) ----------------

__global__ __launch_bounds__(512) void k_scan(int* __restrict__ hist,
                                              int* __restrict__ bhist,
                                              int* __restrict__ bbase,
                                              int* __restrict__ ticket) {
    __shared__ int sh[512];
    __shared__ int amLast;
    int b = blockIdx.x, t = threadIdx.x;
    int v = (t < NBLKA) ? hist[t * NB + b] : 0;
    sh[t] = v;
    __syncthreads();
    for (int off = 1; off < 512; off <<= 1) {
        int a = (t >= off) ? sh[t - off] : 0;
        __syncthreads();
        sh[t] += a;
        __syncthreads();
    }
    if (t < NBLKA) hist[t * NB + b] = sh[t] - v;
    if (t == 511) atomicExch(&bhist[b], sh[511]);
    __syncthreads();
    if (t == 0) {
        __threadfence();
        amLast = (atomicAdd(ticket, 1) == NB - 1) ? 1 : 0;
    }
    __syncthreads();
    if (amLast) {
        int v2 = (t < NB) ? atomicAdd(&bhist[t], 0) : 0;
        __syncthreads();
        sh[t] = v2;
        __syncthreads();
        for (int off = 1; off < 512; off <<= 1) {
            int a = (t >= off) ? sh[t - off] : 0;
            __syncthreads();
            sh[t] += a;
            __syncthreads();
        }
        if (t < NB) bbase[t] = sh[t] - v2;
        if (t == NB - 1) bbase[NB] = sh[t];
    }
}

// scatter only. ebuf packed: (src << 8) | (dst & 255)  (src < 2^17, fits 25 bits)
__global__ __launch_bounds__(256) void k_pairs(const int* __restrict__ src,
                                               const int* __restrict__ dst,
                                               const int* __restrict__ hist,
                                               const int* __restrict__ bbase,
                                               int* __restrict__ ebuf) {
    __shared__ int lh[NB];
    __shared__ int lbase[NB];
    int t = threadIdx.x;
    for (int i = t; i < NB; i += 256) {
        lh[i] = 0;
        lbase[i] = bbase[i] + hist[blockIdx.x * NB + i];
    }
    __syncthreads();
    int e0 = blockIdx.x * EPB;
    int e1 = min(e0 + EPB, NE);
    for (int e = e0 + t; e < e1; e += 256) {
        int s = src[e], d = dst[e];
        int bk = d >> 8;
        int off = atomicAdd(&lh[bk], 1);
        ebuf[lbase[bk] + off] = (s << 8) | (d & 255);
    }
}

// col stores BYTE offsets (src*DF) for gather fp8 table (128 B rows)
__global__ __launch_bounds__(256) void k_build(const int* __restrict__ ebuf,
                                               const int* __restrict__ bbase,
                                               int* __restrict__ rowptr,
                                               float* __restrict__ dinv,
                                               int* __restrict__ col) {
    __shared__ int deg[256];
    __shared__ int lst[256];
    int b = blockIdx.x, t = threadIdx.x;
    int node = (b << 8) + t;
    deg[t] = 0;
    __syncthreads();
    int e0 = bbase[b], e1 = bbase[b + 1];
    for (int e = e0 + t; e < e1; e += 256) atomicAdd(&deg[ebuf[e] & 255], 1);
    __syncthreads();
    int v = deg[t];
    lst[t] = v;
    __syncthreads();
    for (int off = 1; off < 256; off <<= 1) {
        int a = (t >= off) ? lst[t - off] : 0;
        __syncthreads();
        lst[t] += a;
        __syncthreads();
    }
    int mystart = e0 + lst[t] - v;
    if (node < NN) {
        rowptr[node] = mystart;
        dinv[node] = rsqrtf((float)(v + 1));  // +1 self-loop
    }
    if (b == NB - 1 && t == 255) rowptr[NN] = e1;
    lst[t] = mystart;
    __syncthreads();
    for (int e = e0 + t; e < e1; e += 256) {
        int pk = ebuf[e];
        int p = atomicAdd(&lst[pk & 255], 1);
        col[p] = (pk >> 8) * DF;
    }
}

// ---------------- per-layer compute ----------------

// shared MFMA+scale+fp8-pack core for the gemm kernels
__device__ __forceinline__ void gemm_core(const short8* af,
                                          const unsigned short* __restrict__ Wb,
                                          const float* __restrict__ dinv,
                                          int lane, int lm, int orow,
                                          unsigned char* __restrict__ fs8) {
    float dv[4];
#pragma unroll
    for (int j = 0; j < 4; j++) dv[j] = (orow + j < NN) ? dinv[orow + j] : 0.f;

    float res[4][8];
#pragma unroll
    for (int tt = 0; tt < 8; tt++) {
        floatx4 acc = {0.f, 0.f, 0.f, 0.f};
        const unsigned short* wp = Wb + ((size_t)(tt * 4) * 64 + lane) * 8;
        acc = __builtin_amdgcn_mfma_f32_16x16x32_bf16(af[0], *(const short8*)(wp), acc, 0, 0, 0);
        acc = __builtin_amdgcn_mfma_f32_16x16x32_bf16(af[1], *(const short8*)(wp + 512), acc, 0, 0, 0);
        acc = __builtin_amdgcn_mfma_f32_16x16x32_bf16(af[2], *(const short8*)(wp + 1024), acc, 0, 0, 0);
        acc = __builtin_amdgcn_mfma_f32_16x16x32_bf16(af[3], *(const short8*)(wp + 1536), acc, 0, 0, 0);
#pragma unroll
        for (int j = 0; j < 4; j++) res[j][tt] = acc[j] * dv[j];
    }

#pragma unroll
    for (int g = 0; g < 2; g++) {
#pragma unroll
        for (int j = 0; j < 4; j++) {
            int r = orow + j;
            if (r >= NN) continue;
            unsigned int w8 = __builtin_amdgcn_cvt_pk_fp8_f32(res[j][g * 4 + 0], res[j][g * 4 + 1], 0, false);
            w8 = __builtin_amdgcn_cvt_pk_fp8_f32(res[j][g * 4 + 2], res[j][g * 4 + 3], w8, true);
            *(unsigned int*)&fs8[(size_t)r * DF + g * 64 + lm * 4] = w8;
        }
    }
}

// layer-1 gemm: reads x (f32) directly, converts to bf16 in-register.
__global__ __launch_bounds__(256) void k_gemm1(const float* __restrict__ X,
                                               const unsigned short* __restrict__ Wb,
                                               const float* __restrict__ dinv,
                                               unsigned char* __restrict__ fs8) {
    int t = threadIdx.x;
    int wave = t >> 6, l = t & 63;
    int r0 = blockIdx.x * 64 + wave * 16;
    int lm = l & 15, q = l >> 4;

    int arow = r0 + lm;
    if (arow >= NN) arow = NN - 1;
    const float* xrow = X + (size_t)arow * DF + q * 8;
    short8 af[4];
#pragma unroll
    for (int s = 0; s < 4; s++) {
        float4 f0 = *(const float4*)(xrow + s * 32);
        float4 f1 = *(const float4*)(xrow + s * 32 + 4);
        unsigned short o[8] = {f2bf(f0.x), f2bf(f0.y), f2bf(f0.z), f2bf(f0.w),
                               f2bf(f1.x), f2bf(f1.y), f2bf(f1.z), f2bf(f1.w)};
        af[s] = *(short8*)o;
    }
    gemm_core(af, Wb, dinv, l, lm, r0 + q * 4, fs8);
}

// layers 2-3 gemm: reads bf16 activations (physical layout), Wb in phi k-order.
__global__ __launch_bounds__(256) void k_gemm(const unsigned short* __restrict__ X,
                                              const unsigned short* __restrict__ Wb,
                                              const float* __restrict__ dinv,
                                              unsigned char* __restrict__ fs8) {
    int t = threadIdx.x;
    int wave = t >> 6, l = t & 63;
    int r0 = blockIdx.x * 64 + wave * 16;
    int lm = l & 15, q = l >> 4;

    int arow = r0 + lm;
    if (arow >= NN) arow = NN - 1;
    const unsigned short* xrow = X + (size_t)arow * DF + q * 8;
    short8 af[4];
#pragma unroll
    for (int s = 0; s < 4; s++) af[s] = *(const short8*)(xrow + s * 32);
    gemm_core(af, Wb, dinv, l, lm, r0 + q * 4, fs8);
}

// aggregation core: unclamped col reads (col padded by 8 zeros; mid-list
// overreads hit the next node's valid entries). One base address + immediate
// offsets for the 8 col loads; accumulate stays predicated (bit-identical).
__device__ __forceinline__ void agg_node(const unsigned char* __restrict__ fsl, // fs8 + foff
                                         const int* __restrict__ colb,
                                         size_t selfoff, int e0, int e1,
                                         float dvn, const float* bias,
                                         float* o) {
    floatx2 acc0 = {0.f, 0.f}, acc1 = {0.f, 0.f}, acc2 = {0.f, 0.f}, acc3 = {0.f, 0.f};
    for (int base = e0; base < e1; base += 8) {
        const int* cp = colb + base;
        int cb[8];
#pragma unroll
        for (int k = 0; k < 8; k++) cb[k] = cp[k];
        uint2 vv[8];
#pragma unroll
        for (int k = 0; k < 8; k++) vv[k] = *(const uint2*)(fsl + cb[k]);
#pragma unroll
        for (int k = 0; k < 8; k++) {
            if (base + k < e1) {
                acc0 += __builtin_amdgcn_cvt_pk_f32_fp8(vv[k].x, false);
                acc1 += __builtin_amdgcn_cvt_pk_f32_fp8(vv[k].x, true);
                acc2 += __builtin_amdgcn_cvt_pk_f32_fp8(vv[k].y, false);
                acc3 += __builtin_amdgcn_cvt_pk_f32_fp8(vv[k].y, true);
            }
        }
    }
    // self-loop row (fp8, dinv[src] already folded in)
    uint2 sv = *(const uint2*)(fsl + selfoff);
    acc0 += __builtin_amdgcn_cvt_pk_f32_fp8(sv.x, false);
    acc1 += __builtin_amdgcn_cvt_pk_f32_fp8(sv.x, true);
    acc2 += __builtin_amdgcn_cvt_pk_f32_fp8(sv.y, false);
    acc3 += __builtin_amdgcn_cvt_pk_f32_fp8(sv.y, true);

    float a[8] = {acc0.x, acc0.y, acc1.x, acc1.y, acc2.x, acc2.y, acc3.x, acc3.y};
#pragma unroll
    for (int j = 0; j < 8; j++) o[j] = fmaxf(dvn * a[j] + bias[j], 0.f);
}

// 4 nodes per wave, each 16-lane sub owns one node. Permuted bias table (bp)
// replaces 8 runtime phi() evaluations with two aligned float4 loads.
__global__ __launch_bounds__(256) void k_agg(const unsigned char* __restrict__ fs8,
                                             const int* __restrict__ colb,
                                             const int* __restrict__ rowptr,
                                             const float* __restrict__ dinv,
                                             const float* __restrict__ bp,
                                             unsigned short* __restrict__ out) {
    int w = (int)((blockIdx.x * (size_t)blockDim.x + threadIdx.x) >> 6);
    int lane = threadIdx.x & 63;
    int sub = lane >> 4;
    int fo = lane & 15;
    int foff = fo * 8;
    int n = w * 4 + sub;

    float4 bA = *(const float4*)&bp[foff];
    float4 bB = *(const float4*)&bp[foff + 4];
    float bias[8] = {bA.x, bA.y, bA.z, bA.w, bB.x, bB.y, bB.z, bB.w};
    float dvn = dinv[n];
    int e0 = rowptr[n], e1 = rowptr[n + 1];

    float o[8];
    agg_node(fs8 + foff, colb, (size_t)n * DF, e0, e1, dvn, bias, o);

    uint4 pk;
    pk.x = (unsigned int)f2bf(o[0]) | ((unsigned int)f2bf(o[1]) << 16);
    pk.y = (unsigned int)f2bf(o[2]) | ((unsigned int)f2bf(o[3]) << 16);
    pk.z = (unsigned int)f2bf(o[4]) | ((unsigned int)f2bf(o[5]) << 16);
    pk.w = (unsigned int)f2bf(o[6]) | ((unsigned int)f2bf(o[7]) << 16);
    *(uint4*)&out[(size_t)n * DF + foff] = pk;
}

// ---------------- pooling + FC ----------------

__global__ __launch_bounds__(256) void k_poolA(const unsigned short* __restrict__ h,
                                               const int* __restrict__ gstart,
                                               float* __restrict__ part) {
    __shared__ float2 red[256];
    int g = blockIdx.x >> 3, c = blockIdx.x & 7;
    int s = gstart[g], e = gstart[g + 1];
    int len = e - s;
    int cs = s + (int)(((long long)len * c) >> 3);
    int ce = s + (int)(((long long)len * (c + 1)) >> 3);
    int t = threadIdx.x;
    int fp = t & 63;
    int rs = t >> 6;
    float2 acc = make_float2(0.f, 0.f);
    for (int n = cs + rs; n < ce; n += 4) {
        unsigned int v = *(const unsigned int*)&h[(size_t)n * DF + fp * 2];
        acc.x += bf2f_lo(v);
        acc.y += bf2f_hi(v);
    }
    red[t] = acc;
    __syncthreads();
    if (rs == 0) {
        float2 a0 = red[fp], a1 = red[fp + 64], a2 = red[fp + 128], a3 = red[fp + 192];
        float2 o;
        o.x = (a0.x + a1.x) + (a2.x + a3.x);
        o.y = (a0.y + a1.y) + (a2.y + a3.y);
        *(float2*)&part[(size_t)blockIdx.x * DF + fp * 2] = o;
    }
}

// phase B + FC fused: reduce partials -> pooled (LDS, un-permuted) -> FC
__global__ __launch_bounds__(128) void k_poolfc(const float* __restrict__ part,
                                                const int* __restrict__ gstart,
                                                const float* __restrict__ Wfc,
                                                const float* __restrict__ bfc,
                                                float* __restrict__ out) {
    __shared__ float pl[DF];
    int g = blockIdx.x;
    int f = threadIdx.x;
    float s = 0.f;
#pragma unroll
    for (int c = 0; c < PCH; c++) s += part[(size_t)(g * PCH + c) * DF + f];
    int cnt = gstart[g + 1] - gstart[g];
    pl[phi(f)] = s / (float)max(cnt, 1);
    __syncthreads();
    if (f < DOUT) {
        float acc = bfc[f];
        for (int k = 0; k < DF; k++) acc += pl[k] * Wfc[k * DOUT + f];
        out[g * DOUT + f] = acc;
    }
}

// ---------------- launch ----------------

extern "C" void kernel_launch(void* const* d_in, const int* in_sizes, int n_in,
                              void* d_out, int out_size, void* d_ws, size_t ws_size,
                              hipStream_t stream) {
    const float* x     = (const float*)d_in[0];
    const int*   ei    = (const int*)d_in[1];
    const int*   batch = (const int*)d_in[2];
    const float* W1 = (const float*)d_in[3];
    const float* b1 = (const float*)d_in[4];
    const float* W2 = (const float*)d_in[5];
    const float* b2 = (const float*)d_in[6];
    const float* W3 = (const float*)d_in[7];
    const float* b3 = (const float*)d_in[8];
    const float* Wfc = (const float*)d_in[9];
    const float* bfc = (const float*)d_in[10];
    float* out = (float*)d_out;

    char* p = (char*)d_ws;
    unsigned short* ob = (unsigned short*)p;  p += (size_t)NN * DF * sizeof(short);
    unsigned char*  fs8 = (unsigned char*)p;  p += (size_t)NN * DF + 256;
    unsigned short* Wb1 = (unsigned short*)p; p += 16384 * sizeof(short);
    unsigned short* Wb2 = (unsigned short*)p; p += 16384 * sizeof(short);
    unsigned short* Wb3 = (unsigned short*)p; p += 16384 * sizeof(short);
    float* dinv = (float*)p;           p += (size_t)NN * sizeof(float);
    int* rowptr = (int*)p;             p += (size_t)(NN + 4) * sizeof(int);
    int* col    = (int*)p;             p += (size_t)(NE + 8) * sizeof(int);
    int* ebuf   = (int*)p;             p += (size_t)NE * sizeof(int);
    int* bhist  = (int*)p;             p += (size_t)(NB + 4) * sizeof(int);
    int* bbase  = (int*)p;             p += (size_t)(NB + 4) * sizeof(int);
    int* hist   = (int*)p;             p += (size_t)NBLKA * NB * sizeof(int);
    int* gstart = (int*)p;             p += (size_t)(NG + 4) * sizeof(int);
    int* ticket = (int*)p;             p += 4 * sizeof(int);
    float* bp   = (float*)p;           p += 384 * sizeof(float);
    float* part = (float*)p;           p += (size_t)NG * PCH * DF * sizeof(float);

    const int* e_src = ei;
    const int* e_dst = ei + NE;

    // init (hist + bounds + ticket/pad/bias + 3x prepw), merged scans, scatter, CSR build
    k_init<<<NBLKA + 26, 256, 0, stream>>>(e_dst, hist, batch, gstart, ticket, col,
                                           b1, b2, b3, bp,
                                           W1, W2, W3, Wb1, Wb2, Wb3);
    k_scan<<<NB, 512, 0, stream>>>(hist, bhist, bbase, ticket);
    k_pairs<<<NBLKA, 256, 0, stream>>>(e_src, e_dst, hist, bbase, ebuf);
    k_build<<<NB, 256, 0, stream>>>(ebuf, bbase, rowptr, dinv, col);

    int ggrid = (NN + 63) / 64;

    // layer 1 (direct f32 x), layers 2-3 (bf16 activations)
    k_gemm1<<<ggrid, 256, 0, stream>>>(x, Wb1, dinv, fs8);
    k_agg<<<NAGB, 256, 0, stream>>>(fs8, col, rowptr, dinv, bp, ob);
    k_gemm<<<ggrid, 256, 0, stream>>>(ob, Wb2, dinv, fs8);
    k_agg<<<NAGB, 256, 0, stream>>>(fs8, col, rowptr, dinv, bp + 128, ob);
    k_gemm<<<ggrid, 256, 0, stream>>>(ob, Wb3, dinv, fs8);
    k_agg<<<NAGB, 256, 0, stream>>>(fs8, col, rowptr, dinv, bp + 256, ob);

    // pool + fc
    k_poolA<<<NG * PCH, 256, 0, stream>>>(ob, gstart, part);
    k_poolfc<<<NG, 128, 0, stream>>>(part, gstart, Wfc, bfc, out);
}